// Round 3
// baseline (99.082 us; speedup 1.0000x reference)
//
#include <hip/hip_runtime.h>

#define DEVINL __device__ __forceinline__

typedef _Float16 h2_t __attribute__((ext_vector_type(2)));

// ---------------------------------------------------------------------------
// Compile-time circuit constants via GF(2) linear-map tracking.
// Physical index p (10 bits): bits 9..4 = lane (6 bits), bits 3..0 = reg (4).
// Logical amplitude index a = A * p.  CNOT(c,t) => row update, no data motion.
// 1q gate on wire w pairs p with p ^ (A^{-1} e_{9-w}); side = parity(row & p).
// Layer 0 (Rot on product state) is folded into per-wire factors; only gates
// 10..19 run on the full state, as packed-f16 dot2 updates.
// ---------------------------------------------------------------------------
struct GC { int laneXor, regXor, rowL, rowR; };
struct Circ { GC g[20]; int sgnL[10], sgnR[10]; };

constexpr Circ build_circ() {
    Circ c{};
    unsigned A[10] = {};
    for (int i = 0; i < 10; ++i) A[i] = 1u << i;
    for (int w = 0; w < 10; ++w) {
        int pos = 9 - w;
        unsigned m = 1u << pos;
        c.g[w] = GC{ int(m >> 4), int(m & 15u), int(m >> 4), int(m & 15u) };
    }
    for (int q = 0; q < 10; ++q) { int pc = 9 - q, pt = 9 - ((q + 1) % 10); A[pt] ^= A[pc]; }
    unsigned M[10] = {}, Inv[10] = {};
    for (int i = 0; i < 10; ++i) { M[i] = A[i]; Inv[i] = 1u << i; }
    for (int col = 0; col < 10; ++col) {
        int piv = col;
        while (!((M[piv] >> col) & 1u)) ++piv;
        unsigned tm = M[col]; M[col] = M[piv]; M[piv] = tm;
        unsigned ti = Inv[col]; Inv[col] = Inv[piv]; Inv[piv] = ti;
        for (int r = 0; r < 10; ++r)
            if (r != col && ((M[r] >> col) & 1u)) { M[r] ^= M[col]; Inv[r] ^= Inv[col]; }
    }
    for (int w = 0; w < 10; ++w) {
        int pos = 9 - w;
        unsigned m = 0;
        for (int i = 0; i < 10; ++i) m |= ((Inv[i] >> pos) & 1u) << i;
        unsigned row = A[pos];
        c.g[10 + w] = GC{ int(m >> 4), int(m & 15u), int(row >> 4), int(row & 15u) };
    }
    for (int q = 0; q < 10; ++q) { int pc = 9 - q, pt = 9 - ((q + 2) % 10); A[pt] ^= A[pc]; }
    for (int q = 0; q < 10; ++q) { unsigned row = A[9 - q]; c.sgnL[q] = int(row >> 4); c.sgnR[q] = int(row & 15u); }
    return c;
}

constexpr Circ CC = build_circ();

DEVINL float csign(float v, int s) {
    return __int_as_float(__float_as_int(v) ^ (s << 31));
}

// packed f16 helpers
DEVINL int pk(float a, float b) {
    return __builtin_bit_cast(int, __builtin_amdgcn_cvt_pkrtz(a, b));
}
DEVINL float fdot2(int p, int v, float acc) {
    return __builtin_amdgcn_fdot2(__builtin_bit_cast(h2_t, p), __builtin_bit_cast(h2_t, v), acc, false);
}

// lane-xor fetch of a 32-bit value: DPP quad_perm for 1..3, ds_swizzle <32, else bpermute
template<int XOR>
DEVINL int lxi(int x, int lane) {
    if constexpr (XOR == 1)      return __builtin_amdgcn_update_dpp(0, x, 0xB1, 0xF, 0xF, true);
    else if constexpr (XOR == 2) return __builtin_amdgcn_update_dpp(0, x, 0x4E, 0xF, 0xF, true);
    else if constexpr (XOR == 3) return __builtin_amdgcn_update_dpp(0, x, 0x1B, 0xF, 0xF, true);
    else if constexpr (XOR < 32) return __builtin_amdgcn_ds_swizzle(x, 0x1F | (XOR << 10));
    else                         return __builtin_amdgcn_ds_bpermute((lane ^ XOR) << 2, x);
}
template<int XOR>
DEVINL float lxf(float v, int lane) {
    return __int_as_float(lxi<XOR>(__float_as_int(v), lane));
}

// Apply gates G..19 on packed (re,im) f16 amplitudes via v_dot2_f32_f16.
// smP[G*4..]: P1=(fAr,-fAi) P2=(fBr,-fBi) P3=(fAi,fAr) P4=(fBi,fBr) as f16x2.
// Lane sign sL flips fAi (P1 bit31, P3 bit15) and fBr (P2 bit15, P4 bit31).
// Reg sign cR=1 variants: P1^0x80000000, P2^0x8000, P3^0x8000, P4^0x80000000.
template<int G>
DEVINL void gates(int (&a)[16], const int* smP, int lane) {
    if constexpr (G < 20) {
        constexpr GC gc = CC.g[G];
        int sL = __popc(unsigned(lane & gc.rowL)) & 1;
        int p1 = smP[G * 4 + 0] ^ (sL << 31);
        int p2 = smP[G * 4 + 1] ^ (sL << 15);
        int p3 = smP[G * 4 + 2] ^ (sL << 15);
        int p4 = smP[G * 4 + 3] ^ (sL << 31);
        int q1 = p1 ^ (int)0x80000000;
        int q2 = p2 ^ 0x8000;
        int q3 = p3 ^ 0x8000;
        int q4 = p4 ^ (int)0x80000000;
        int b_[16];
        if constexpr (gc.laneXor == 0) {
            #pragma unroll
            for (int r = 0; r < 16; ++r) b_[r] = a[r ^ gc.regXor];
        } else {
            #pragma unroll
            for (int r = 0; r < 16; ++r) b_[r] = lxi<gc.laneXor>(a[r ^ gc.regXor], lane);
        }
        #pragma unroll
        for (int r = 0; r < 16; ++r) {
            const int cR = __builtin_popcount(unsigned(gc.rowR & r)) & 1;  // folds after unroll
            float nr = fdot2(cR ? q1 : p1, a[r], fdot2(cR ? q2 : p2, b_[r], 0.f));
            float ni = fdot2(cR ? q3 : p3, a[r], fdot2(cR ? q4 : p4, b_[r], 0.f));
            a[r] = pk(nr, ni);
        }
        gates<G + 1>(a, smP, lane);
    }
}

__global__ __launch_bounds__(256) void qsim(const float* __restrict__ x,
                                            const float* __restrict__ qw,
                                            float* __restrict__ out, int B) {
    // sm32: f32 Rot entries (u00r,u00i,u01r,u01i) for the embedding fold.
    // smP : packed-f16 dot2 coefficient quads for the full-state gates.
    __shared__ float sm32[80];
    __shared__ int smP[80];
    {
        int g = threadIdx.x;
        if (g < 20) {
            float phi = qw[g * 3 + 0], th = qw[g * 3 + 1], om = qw[g * 3 + 2];
            float c = cosf(0.5f * th), s = sinf(0.5f * th);
            float apo = 0.5f * (phi + om), amo = 0.5f * (phi - om);
            float m0 =  cosf(apo) * c;   // fAr
            float m1 = -sinf(apo) * c;   // fAi
            float m2 = -cosf(amo) * s;   // fBr
            float m3 = -sinf(amo) * s;   // fBi
            sm32[g * 4 + 0] = m0; sm32[g * 4 + 1] = m1;
            sm32[g * 4 + 2] = m2; sm32[g * 4 + 3] = m3;
            smP[g * 4 + 0] = pk(m0, -m1);
            smP[g * 4 + 1] = pk(m2, -m3);
            smP[g * 4 + 2] = pk(m1,  m0);
            smP[g * 4 + 3] = pk(m3,  m2);
        }
    }
    __syncthreads();

    int lane = threadIdx.x & 63;
    int b = __builtin_amdgcn_readfirstlane(blockIdx.x * 4 + (threadIdx.x >> 6));
    if (b >= B) return;

    // ---- embedding + layer-0 Rot folded into per-wire complex factors (fp32)
    const float* xb = x + b * 10;
    float f0r[10], f0i[10], f1r[10], f1i[10];
    #pragma unroll
    for (int w = 0; w < 10; ++w) {
        float h = 0.5f * xb[w];
        float s = __sinf(h), c = __cosf(h);
        float m0 = sm32[w * 4 + 0], m1 = sm32[w * 4 + 1], m2 = sm32[w * 4 + 2], m3 = sm32[w * 4 + 3];
        f0r[w] =  m0 * c + m2 * s;
        f0i[w] =  m1 * c + m3 * s;
        f1r[w] = -m2 * c + m0 * s;
        f1i[w] =  m3 * c - m1 * s;
    }
    float lfr, lfi;
    {
        int bit = lane & 1;
        lfr = bit ? f1r[5] : f0r[5];
        lfi = bit ? f1i[5] : f0i[5];
    }
    #pragma unroll
    for (int jj = 1; jj < 6; ++jj) {
        int w = 5 - jj;
        int bit = (lane >> jj) & 1;
        float pr = bit ? f1r[w] : f0r[w];
        float pi = bit ? f1i[w] : f0i[w];
        float nr = lfr * pr - lfi * pi;
        float ni = lfr * pi + lfi * pr;
        lfr = nr; lfi = ni;
    }
    float t01r[4], t01i[4], t23r[4], t23i[4];
    #pragma unroll
    for (int v = 0; v < 4; ++v) {
        float ar9 = (v & 1) ? f1r[9] : f0r[9], ai9 = (v & 1) ? f1i[9] : f0i[9];
        float ar8 = (v >> 1) ? f1r[8] : f0r[8], ai8 = (v >> 1) ? f1i[8] : f0i[8];
        t01r[v] = ar9 * ar8 - ai9 * ai8;
        t01i[v] = ar9 * ai8 + ai9 * ar8;
        float ar7 = (v & 1) ? f1r[7] : f0r[7], ai7 = (v & 1) ? f1i[7] : f0i[7];
        float ar6 = (v >> 1) ? f1r[6] : f0r[6], ai6 = (v >> 1) ? f1i[6] : f0i[6];
        t23r[v] = ar7 * ar6 - ai7 * ai6;
        t23i[v] = ar7 * ai6 + ai7 * ar6;
    }
    float g4r[4], g4i[4];
    #pragma unroll
    for (int v = 0; v < 4; ++v) {
        g4r[v] = lfr * t01r[v] - lfi * t01i[v];
        g4i[v] = lfr * t01i[v] + lfi * t01r[v];
    }
    int a[16];                       // packed (re,im) f16 amplitudes
    #pragma unroll
    for (int r = 0; r < 16; ++r) {
        float ar = g4r[r & 3] * t23r[r >> 2] - g4i[r & 3] * t23i[r >> 2];
        float ai = g4r[r & 3] * t23i[r >> 2] + g4i[r & 3] * t23r[r >> 2];
        a[r] = pk(ar, ai);
    }

    // ---- layer-1 Rot gates (CNOT rings folded into compile-time index algebra)
    gates<10>(a, smP, lane);

    // ---- probs (f32 via dot2 of amp with itself), then 4-bit WHT over regs:
    // W[m] = sum_r (-1)^{popc(m&r)} prob[r] gives all 16 reg-sign patterns.
    float t[16];
    #pragma unroll
    for (int r = 0; r < 16; ++r) t[r] = fdot2(a[r], a[r], 0.f);
    #pragma unroll
    for (int bit = 1; bit < 16; bit <<= 1) {
        #pragma unroll
        for (int i = 0; i < 16; ++i) {
            if ((i & bit) == 0) {
                float u = t[i], v = t[i | bit];
                t[i] = u + v;
                t[i | bit] = u - v;
            }
        }
    }
    float e[10];
    #pragma unroll
    for (int q = 0; q < 10; ++q) {
        int sl = __popc(unsigned(lane & CC.sgnL[q])) & 1;
        e[q] = csign(t[CC.sgnR[q]], sl);
    }
    #pragma unroll
    for (int q = 0; q < 10; ++q) {
        e[q] += lxf<1>(e[q], lane);
        e[q] += lxf<2>(e[q], lane);
        e[q] += lxf<4>(e[q], lane);
        e[q] += lxf<8>(e[q], lane);
        e[q] += lxf<16>(e[q], lane);
        e[q] += lxf<32>(e[q], lane);
    }
    float v = e[0];
    #pragma unroll
    for (int q = 1; q < 10; ++q) v = (lane == q) ? e[q] : v;
    if (lane < 10) out[b * 10 + lane] = v;
}

extern "C" void kernel_launch(void* const* d_in, const int* in_sizes, int n_in,
                              void* d_out, int out_size, void* d_ws, size_t ws_size,
                              hipStream_t stream) {
    const float* x  = (const float*)d_in[0];
    const float* qw = (const float*)d_in[1];
    float* out = (float*)d_out;
    int B = in_sizes[0] / 10;
    int blocks = (B + 3) / 4;   // 4 samples (waves) per 256-thread block
    hipLaunchKernelGGL(qsim, dim3(blocks), dim3(256), 0, stream, x, qw, out, B);
}